// Round 1
// baseline (264.545 us; speedup 1.0000x reference)
//
#include <hip/hip_runtime.h>

#define KTOP 100
#define NCOL 16384
#define TPB  256
#define VITER (NCOL / (TPB * 4))   // 16 float4 per thread

__device__ __forceinline__ unsigned encode_key(float f) {
    unsigned u = __float_as_uint(f);
    unsigned m = ((unsigned)((int)u >> 31)) | 0x80000000u;  // neg: all-ones, pos: MSB
    return u ^ m;
}
__device__ __forceinline__ float decode_key(unsigned k) {
    unsigned m = (k & 0x80000000u) ? 0x80000000u : 0xFFFFFFFFu;
    return __uint_as_float(k ^ m);
}

__global__ __launch_bounds__(TPB)
void topk_act_kernel(const float* __restrict__ x, float* __restrict__ out) {
    extern __shared__ unsigned keys[];        // NCOL sortable keys (64 KB)
    __shared__ unsigned hist[256];
    __shared__ unsigned scan_arr[256];
    __shared__ unsigned s_byte, s_k, s_eq;
    __shared__ unsigned wtot[TPB / 64];
    __shared__ unsigned run_cnt;

    const int row = blockIdx.x;
    const int tid = threadIdx.x;
    const float4* __restrict__ xrow = (const float4*)(x + (size_t)row * NCOL);
    float4* __restrict__ orow = (float4*)(out + (size_t)row * NCOL);

    // ---- stage row into LDS as sortable keys (only HBM read) ----
    #pragma unroll
    for (int j = 0; j < VITER; ++j) {
        int i = tid + j * TPB;
        float4 v = xrow[i];
        uint4 kv;
        kv.x = encode_key(v.x); kv.y = encode_key(v.y);
        kv.z = encode_key(v.z); kv.w = encode_key(v.w);
        ((uint4*)keys)[i] = kv;
    }
    __syncthreads();

    // ---- 4-pass radix select for the K-th largest key ----
    unsigned pref = 0;      // selected high bits so far
    unsigned k_cur = KTOP;  // rank remaining within current candidate set
    unsigned eq_cnt = 0;    // candidates equal to final T

    #pragma unroll
    for (int p = 0; p < 4; ++p) {
        const int shift = 24 - 8 * p;
        const unsigned hi_mask = p ? (0xFFFFFFFFu << (32 - 8 * p)) : 0u;

        hist[tid] = 0;
        __syncthreads();

        for (int j = 0; j < VITER; ++j) {
            uint4 kv = ((const uint4*)keys)[tid + j * TPB];
            if (((kv.x ^ pref) & hi_mask) == 0) atomicAdd(&hist[(kv.x >> shift) & 0xFFu], 1u);
            if (((kv.y ^ pref) & hi_mask) == 0) atomicAdd(&hist[(kv.y >> shift) & 0xFFu], 1u);
            if (((kv.z ^ pref) & hi_mask) == 0) atomicAdd(&hist[(kv.z >> shift) & 0xFFu], 1u);
            if (((kv.w ^ pref) & hi_mask) == 0) atomicAdd(&hist[(kv.w >> shift) & 0xFFu], 1u);
        }
        __syncthreads();

        // suffix-inclusive scan: C[t] = # candidates with byte >= t
        unsigned h = hist[tid];
        scan_arr[tid] = h;
        __syncthreads();
        for (int stride = 1; stride < 256; stride <<= 1) {
            unsigned v = (tid + stride < 256) ? scan_arr[tid + stride] : 0u;
            __syncthreads();
            scan_arr[tid] += v;
            __syncthreads();
        }
        unsigned Ct = scan_arr[tid];
        unsigned Cn = (tid < 255) ? scan_arr[tid + 1] : 0u;
        if (Ct >= k_cur && Cn < k_cur) {   // exactly one thread matches
            s_byte = (unsigned)tid;
            s_k    = k_cur - Cn;           // rank remaining within this bin
            s_eq   = h;                    // bin population (== #equals on last pass)
        }
        __syncthreads();
        pref |= s_byte << shift;
        k_cur = s_k;
        eq_cnt = s_eq;
        __syncthreads();
    }

    const unsigned T = pref;        // K-th largest key
    const unsigned k_rem = k_cur;   // how many elements equal to T to keep

    if (k_rem == eq_cnt) {
        // ---- fast path: keep everything >= T (no boundary tie dropped) ----
        #pragma unroll
        for (int j = 0; j < VITER; ++j) {
            int i = tid + j * TPB;
            uint4 kv = ((const uint4*)keys)[i];
            float4 o;
            o.x = (kv.x >= T) ? decode_key(kv.x) : 0.0f;
            o.y = (kv.y >= T) ? decode_key(kv.y) : 0.0f;
            o.z = (kv.z >= T) ? decode_key(kv.z) : 0.0f;
            o.w = (kv.w >= T) ? decode_key(kv.w) : 0.0f;
            orow[i] = o;
        }
    } else {
        // ---- rare stable tie path: keep first k_rem equal elements (index order) ----
        if (tid == 0) run_cnt = 0;
        __syncthreads();
        const int lane = tid & 63;
        const int wv = tid >> 6;
        for (int base = 0; base < NCOL; base += TPB) {
            unsigned key = keys[base + tid];
            bool eq = (key == T);
            unsigned long long bal = __ballot(eq);
            if (lane == 0) wtot[wv] = (unsigned)__popcll(bal);
            __syncthreads();
            unsigned off = run_cnt;
            for (int w = 0; w < wv; ++w) off += wtot[w];
            unsigned rank = off + (unsigned)__popcll(bal & ((1ULL << lane) - 1ULL));
            bool keep = (key > T) || (eq && rank < k_rem);
            out[(size_t)row * NCOL + base + tid] = keep ? decode_key(key) : 0.0f;
            __syncthreads();
            if (tid == 0) {
                unsigned s = 0;
                for (int w = 0; w < TPB / 64; ++w) s += wtot[w];
                run_cnt += s;
            }
            __syncthreads();
        }
    }
}

extern "C" void kernel_launch(void* const* d_in, const int* in_sizes, int n_in,
                              void* d_out, int out_size, void* d_ws, size_t ws_size,
                              hipStream_t stream) {
    const float* x = (const float*)d_in[0];
    float* out = (float*)d_out;
    const int B = in_sizes[0] / NCOL;   // 4096 rows
    topk_act_kernel<<<B, TPB, NCOL * sizeof(unsigned), stream>>>(x, out);
}

// Round 2
// 156.515 us; speedup vs baseline: 1.6902x; 1.6902x over previous
//
#include <hip/hip_runtime.h>

#define KTOP 100
#define NCOL 16384
#define TPB  256
#define NCHUNK (NCOL / (TPB * 4))   // 16 uint4 chunks per thread
#define HPAD 264                    // 256 bins + 8 pad words: wave copies hit different banks

// order-preserving key transform (monotone: a<b as float <=> key(a)<key(b) as uint)
__device__ __forceinline__ unsigned enc(unsigned u) {
    return u ^ (((unsigned)((int)u >> 31)) | 0x80000000u);
}
__device__ __forceinline__ unsigned decb(unsigned k) {
    return k ^ ((k & 0x80000000u) ? 0x80000000u : 0xFFFFFFFFu);
}

__global__ __launch_bounds__(TPB, 4)
void topk_act_kernel(const float* __restrict__ x, float* __restrict__ out) {
    __shared__ unsigned hist[4 * HPAD];
    __shared__ unsigned scan_arr[TPB];
    __shared__ unsigned s_byte, s_k, s_eq;

    const int row = blockIdx.x;
    const int tid = threadIdx.x;
    const int lane = tid & 63;
    const int wv = tid >> 6;

    const uint4* __restrict__ xrow = (const uint4*)(x + (size_t)row * NCOL);
    uint4* __restrict__ orow = (uint4*)(out + (size_t)row * NCOL);

    // ---- load row into registers as sortable keys (only HBM read) ----
    uint4 kv[NCHUNK];
    #pragma unroll
    for (int j = 0; j < NCHUNK; ++j) {
        uint4 v = xrow[tid + j * TPB];
        kv[j].x = enc(v.x); kv[j].y = enc(v.y);
        kv[j].z = enc(v.z); kv[j].w = enc(v.w);
    }

    // ---- 4-pass radix select (8 bits/pass), per-wave padded histograms ----
    unsigned pref = 0, kcur = KTOP, eqc = 0;
    unsigned* myhist = hist + wv * HPAD;

    for (int p = 0; p < 4; ++p) {
        const int shift = 24 - 8 * p;
        const unsigned hb = 8u * (unsigned)p;   // # already-resolved high bits

        for (int i = tid; i < 4 * HPAD; i += TPB) hist[i] = 0;
        __syncthreads();

        #pragma unroll
        for (int j = 0; j < NCHUNK; ++j) {
            unsigned k0 = kv[j].x, k1 = kv[j].y, k2 = kv[j].z, k3 = kv[j].w;
            if (hb == 0 || ((k0 ^ pref) >> (32 - hb)) == 0) atomicAdd(&myhist[(k0 >> shift) & 0xFFu], 1u);
            if (hb == 0 || ((k1 ^ pref) >> (32 - hb)) == 0) atomicAdd(&myhist[(k1 >> shift) & 0xFFu], 1u);
            if (hb == 0 || ((k2 ^ pref) >> (32 - hb)) == 0) atomicAdd(&myhist[(k2 >> shift) & 0xFFu], 1u);
            if (hb == 0 || ((k3 ^ pref) >> (32 - hb)) == 0) atomicAdd(&myhist[(k3 >> shift) & 0xFFu], 1u);
        }
        __syncthreads();

        // wave-redundant suffix scan; lane owns bins 4*lane .. 4*lane+3
        unsigned t0 = 0, t1 = 0, t2 = 0, t3 = 0;
        #pragma unroll
        for (int w = 0; w < 4; ++w) {
            const unsigned* h = hist + w * HPAD + 4 * lane;
            t0 += h[0]; t1 += h[1]; t2 += h[2]; t3 += h[3];
        }
        unsigned own = t0 + t1 + t2 + t3;
        unsigned incl = own;
        #pragma unroll
        for (int s = 1; s < 64; s <<= 1) {
            unsigned v = __shfl_down(incl, s);
            if (lane + s < 64) incl += v;
        }
        unsigned above = incl - own;           // candidates in higher bins (lanes > lane)
        unsigned C3 = above + t3;              // inclusive suffix counts per bin
        unsigned C2 = C3 + t2;
        unsigned C1 = C2 + t1;
        unsigned C0 = C1 + t0;
        if (C0 >= kcur && C0 - t0 < kcur) { s_byte = 4u * lane + 0u; s_k = kcur - (C0 - t0); s_eq = t0; }
        if (C1 >= kcur && C1 - t1 < kcur) { s_byte = 4u * lane + 1u; s_k = kcur - (C1 - t1); s_eq = t1; }
        if (C2 >= kcur && C2 - t2 < kcur) { s_byte = 4u * lane + 2u; s_k = kcur - (C2 - t2); s_eq = t2; }
        if (C3 >= kcur && C3 - t3 < kcur) { s_byte = 4u * lane + 3u; s_k = kcur - (C3 - t3); s_eq = t3; }
        __syncthreads();
        pref |= s_byte << shift;
        kcur = s_k;
        eqc = s_eq;
        // next-pass zeroing is followed by a barrier before any s_* rewrite -> safe
    }

    const unsigned T = pref;      // key of K-th largest
    const unsigned krem = kcur;   // # elements == T to keep (stable, by index)

    if (krem == eqc) {
        // ---- fast path: keep everything >= T ----
        #pragma unroll
        for (int j = 0; j < NCHUNK; ++j) {
            uint4 o;
            o.x = (kv[j].x >= T) ? decb(kv[j].x) : 0u;
            o.y = (kv[j].y >= T) ? decb(kv[j].y) : 0u;
            o.z = (kv[j].z >= T) ? decb(kv[j].z) : 0u;
            o.w = (kv[j].w >= T) ? decb(kv[j].w) : 0u;
            orow[tid + j * TPB] = o;
        }
    } else {
        // ---- rare stable tie path: keep first krem equals in index order ----
        unsigned run = 0;
        for (int j = 0; j < NCHUNK; ++j) {
            unsigned e0 = (kv[j].x == T), e1 = (kv[j].y == T);
            unsigned e2 = (kv[j].z == T), e3 = (kv[j].w == T);
            unsigned le = e0 + e1 + e2 + e3;
            scan_arr[tid] = le;
            __syncthreads();
            for (int s = 1; s < TPB; s <<= 1) {
                unsigned v = (tid >= s) ? scan_arr[tid - s] : 0u;
                __syncthreads();
                scan_arr[tid] += v;
                __syncthreads();
            }
            unsigned excl = scan_arr[tid] - le;
            unsigned total = scan_arr[TPB - 1];
            unsigned base = run + excl;
            unsigned r0 = base;
            unsigned r1 = base + e0;
            unsigned r2 = r1 + e1;
            unsigned r3 = r2 + e2;
            uint4 o;
            o.x = (kv[j].x > T || (e0 && r0 < krem)) ? decb(kv[j].x) : 0u;
            o.y = (kv[j].y > T || (e1 && r1 < krem)) ? decb(kv[j].y) : 0u;
            o.z = (kv[j].z > T || (e2 && r2 < krem)) ? decb(kv[j].z) : 0u;
            o.w = (kv[j].w > T || (e3 && r3 < krem)) ? decb(kv[j].w) : 0u;
            orow[tid + j * TPB] = o;
            run += total;
            __syncthreads();
        }
    }
}

extern "C" void kernel_launch(void* const* d_in, const int* in_sizes, int n_in,
                              void* d_out, int out_size, void* d_ws, size_t ws_size,
                              hipStream_t stream) {
    const float* x = (const float*)d_in[0];
    float* out = (float*)d_out;
    const int B = in_sizes[0] / NCOL;   // 4096 rows
    topk_act_kernel<<<B, TPB, 0, stream>>>(x, out);
}